// Round 1
// baseline (971.264 us; speedup 1.0000x reference)
//
#include <hip/hip_runtime.h>
#include <stdint.h>
#include <math.h>

// ---------------------------------------------------------------------------
// MultiheadSdpaDiff3: x[2,2048,2048] -> Q/K/V proj -> differential causal
// attention (H=8 pairs, D=128, V-width 256) -> RMSNorm combine -> @ Wo.
// All matmuls via bf16 MFMA 16x16x32, fp32 accumulate.
// ws layout (bytes):
//   xb   @ 0          : 16777216  (x as bf16, [4096][2048])
//   Wtq  @ 16777216   : 8388608   (Wq^T bf16 [N][K])
//   Wtk  @ 25165824   : 8388608
//   Wtv  @ 33554432   : 8388608
//   Wto  @ 41943040   : 8388608
//   Qb   @ 50331648   : 16777216  (bf16 [4096][2048])
//   Kb   @ 67108864   : 16777216
//   Vb   @ 83886080   : 16777216
//   Vtb  @ 100663296  : 16777216  (per-b transposed V: [b][col][t])
//   o12  @ 117440512  : 67108864  (fp32 [c][b][t][h][256])
//   ob   @ 184549376  : 16777216  (combined+rmsnormed bf16 [4096][2048])
//   lam  @ 201326592  : 256
// total ~201.3 MB
// ---------------------------------------------------------------------------

typedef unsigned short u16;
typedef short bf16x8 __attribute__((ext_vector_type(8)));
typedef float f32x4 __attribute__((ext_vector_type(4)));

typedef uint32_t __attribute__((address_space(1))) as1_u32;
typedef uint32_t __attribute__((address_space(3))) as3_u32;

#define LAMBDA_INIT 0.78360576653162453f

__device__ __forceinline__ u16 f2bf(float f) {
  uint32_t u = __float_as_uint(f);
  u += 0x7FFFu + ((u >> 16) & 1u);   // RNE
  return (u16)(u >> 16);
}

__device__ __forceinline__ void async16(u16* lds, const u16* g) {
  // global -> LDS direct DMA, 16B per lane. LDS dest must be uniform+lane*16.
  __builtin_amdgcn_global_load_lds((const as1_u32*)(uintptr_t)g,
                                   (as3_u32*)(uint32_t)(uintptr_t)lds, 16, 0, 0);
}

__device__ __forceinline__ f32x4 mfma16(bf16x8 a, bf16x8 b, f32x4 c) {
  return __builtin_amdgcn_mfma_f32_16x16x32_bf16(a, b, c, 0, 0, 0);
}

// --------------------------- prep kernels ----------------------------------

__global__ void cast_x_kernel(const float* __restrict__ x, u16* __restrict__ xb, int n4) {
  int i = blockIdx.x * 256 + threadIdx.x;
  if (i < n4) {
    float4 v = ((const float4*)x)[i];
    ushort4 o;
    o.x = f2bf(v.x); o.y = f2bf(v.y); o.z = f2bf(v.z); o.w = f2bf(v.w);
    ((ushort4*)xb)[i] = o;
  }
}

// Wt[n][k] = bf16(W[k][n]); W is [2048][2048] fp32.
__global__ void transpose_w_kernel(const float* __restrict__ W, u16* __restrict__ Wt) {
  __shared__ float tile[32][33];
  int tx = threadIdx.x, ty = threadIdx.y;
  int c0 = blockIdx.x * 32, r0 = blockIdx.y * 32;
#pragma unroll
  for (int i = 0; i < 32; i += 8)
    tile[ty + i][tx] = W[(size_t)(r0 + ty + i) * 2048 + c0 + tx];
  __syncthreads();
#pragma unroll
  for (int i = 0; i < 32; i += 8)
    Wt[(size_t)(c0 + ty + i) * 2048 + r0 + tx] = f2bf(tile[tx][ty + i]);
}

// Per-b transpose of bf16 V: dst[b][col][t] = src[b][t][col]
__global__ void transpose_v_kernel(const u16* __restrict__ V, u16* __restrict__ Vt) {
  __shared__ u16 tile[32][33];
  int b = blockIdx.z;
  const u16* src = V + (size_t)b * 2048 * 2048;
  u16* dst = Vt + (size_t)b * 2048 * 2048;
  int tx = threadIdx.x, ty = threadIdx.y;
  int c0 = blockIdx.x * 32, r0 = blockIdx.y * 32;
#pragma unroll
  for (int i = 0; i < 32; i += 8)
    tile[ty + i][tx] = src[(size_t)(r0 + ty + i) * 2048 + c0 + tx];
  __syncthreads();
#pragma unroll
  for (int i = 0; i < 32; i += 8)
    dst[(size_t)(c0 + ty + i) * 2048 + r0 + tx] = tile[tx][ty + i];
}

__global__ void lam_kernel(const float* __restrict__ lq1, const float* __restrict__ lk1,
                           const float* __restrict__ lq2, const float* __restrict__ lk2,
                           float* __restrict__ out) {
  int L = threadIdx.x;  // 64 threads
  float d1 = lq1[L] * lk1[L] + lq1[L + 64] * lk1[L + 64];
  float d2 = lq2[L] * lk2[L] + lq2[L + 64] * lk2[L + 64];
#pragma unroll
  for (int m = 1; m < 64; m <<= 1) {
    d1 += __shfl_xor(d1, m);
    d2 += __shfl_xor(d2, m);
  }
  if (L == 0) out[0] = __expf(d1) - __expf(d2) + LAMBDA_INIT;
}

// --------------------------- GEMM (m97 structure) --------------------------
// C[M,N] = A[M,K] @ Bt[N,K]^T ; A,Bt bf16 row-major; 128x128 tile, BK=32,
// 256 threads = 4 waves in 2x2, each wave 64x64 (16 MFMA tiles).
template <int OUT_BF16>
__global__ __launch_bounds__(256, 2) void gemm_bt_kernel(const u16* __restrict__ A,
                                                         const u16* __restrict__ Bt,
                                                         void* __restrict__ Cout,
                                                         int M, int N, int K) {
  __shared__ __attribute__((aligned(16))) u16 As[128 * 32];
  __shared__ __attribute__((aligned(16))) u16 Bs[128 * 32];
  int t = threadIdx.x;
  int lane = t & 63, w = t >> 6;
  int lr = lane & 15, lq = lane >> 4;
  int m0 = blockIdx.y * 128, n0 = blockIdx.x * 128;
  int wm = (w >> 1) * 64, wn = (w & 1) * 64;
  const u16* Ab = A + (size_t)m0 * K;
  const u16* Bb = Bt + (size_t)n0 * K;
  f32x4 acc[4][4] = {};
  int r0 = t >> 2;             // staging row for chunk t (chunk = row*4 + kc)
  int kc0 = (t & 3) * 8;       // element offset within row

  for (int k0 = 0; k0 < K; k0 += 32) {
    __syncthreads();
    async16(&As[t * 8], Ab + (size_t)r0 * K + k0 + kc0);
    async16(&Bs[t * 8], Bb + (size_t)r0 * K + k0 + kc0);
    async16(&As[(256 + t) * 8], Ab + (size_t)(64 + r0) * K + k0 + kc0);
    async16(&Bs[(256 + t) * 8], Bb + (size_t)(64 + r0) * K + k0 + kc0);
    __syncthreads();
    bf16x8 a[4], b[4];
#pragma unroll
    for (int mi = 0; mi < 4; mi++)
      a[mi] = *(const bf16x8*)&As[(wm + mi * 16 + lr) * 32 + lq * 8];
#pragma unroll
    for (int ni = 0; ni < 4; ni++)
      b[ni] = *(const bf16x8*)&Bs[(wn + ni * 16 + lr) * 32 + lq * 8];
#pragma unroll
    for (int mi = 0; mi < 4; mi++)
#pragma unroll
      for (int ni = 0; ni < 4; ni++)
        acc[mi][ni] = mfma16(a[mi], b[ni], acc[mi][ni]);
  }
  // epilogue: C/D layout col=lane&15, row=(lane>>4)*4+reg
#pragma unroll
  for (int mi = 0; mi < 4; mi++) {
#pragma unroll
    for (int ni = 0; ni < 4; ni++) {
#pragma unroll
      for (int r = 0; r < 4; r++) {
        int row = m0 + wm + mi * 16 + lq * 4 + r;
        int col = n0 + wn + ni * 16 + lr;
        if (OUT_BF16)
          ((u16*)Cout)[(size_t)row * N + col] = f2bf(acc[mi][ni][r]);
        else
          ((float*)Cout)[(size_t)row * N + col] = acc[mi][ni][r];
      }
    }
  }
}

// --------------------------- flash attention -------------------------------
// One block per (q-tile 64 rows, b*8+h, component c). 256 threads = 4 waves.
// Wave w owns S columns [w*16,w*16+16) and O columns e in [w*64,(w+1)*64).
__global__ __launch_bounds__(256, 1) void flash_diff_kernel(const u16* __restrict__ Qb,
                                                            const u16* __restrict__ Kb,
                                                            const u16* __restrict__ Vt,
                                                            float* __restrict__ o12) {
  __shared__ __attribute__((aligned(16))) u16 Qs[64 * 136];   // stride 272B
  __shared__ __attribute__((aligned(16))) u16 Ks[64 * 136];
  __shared__ __attribute__((aligned(16))) u16 Vs[256 * 72];   // V^T tile, stride 144B
  __shared__ __attribute__((aligned(16))) u16 Ps[64 * 72];
  __shared__ float redm[256];
  __shared__ float reds[256];
  __shared__ float mL[64], lL[64];

  int t = threadIdx.x;
  int lane = t & 63, w = t >> 6, lr = lane & 15, lq = lane >> 4;
  int qi = blockIdx.x, bh = blockIdx.y, c = blockIdx.z;
  int b = bh >> 3, h = bh & 7;
  int q0 = qi * 64;
  const u16* Qp = Qb + (size_t)b * 2048 * 2048 + h * 256 + c * 128;
  const u16* Kp = Kb + (size_t)b * 2048 * 2048 + h * 256 + c * 128;
  const u16* Vp = Vt + ((size_t)b * 2048 + h * 256) * 2048;

  if (t < 64) { mL[t] = -INFINITY; lL[t] = 0.0f; }
  // stage Q tile [64][128]
#pragma unroll
  for (int i = 0; i < 4; i++) {
    int ci = i * 256 + t, row = ci >> 4, u = (ci & 15) * 8;
    *(uint4*)&Qs[row * 136 + u] = *(const uint4*)(Qp + (size_t)(q0 + row) * 2048 + u);
  }
  f32x4 acc[4][4] = {};  // [mi][ei]
  const float sscale = 0.088388347648318447f;  // 1/sqrt(128)

  for (int j = 0; j <= qi; j++) {
    __syncthreads();  // protect LDS reuse (covers Q staging on first iter)
    // stage K tile [64][128]
#pragma unroll
    for (int i = 0; i < 4; i++) {
      int ci = i * 256 + t, row = ci >> 4, u = (ci & 15) * 8;
      *(uint4*)&Ks[row * 136 + u] = *(const uint4*)(Kp + (size_t)(j * 64 + row) * 2048 + u);
    }
    // stage V^T tile [256 e][64 n]
#pragma unroll
    for (int i = 0; i < 8; i++) {
      int ci = i * 256 + t, e = ci >> 3, u = (ci & 7) * 8;
      *(uint4*)&Vs[e * 72 + u] = *(const uint4*)(Vp + (size_t)e * 2048 + j * 64 + u);
    }
    __syncthreads();
    // S = Q K^T  (wave w -> cols w*16..+16, rows 0..63)
    f32x4 sacc[4] = {};
#pragma unroll
    for (int ks = 0; ks < 4; ks++) {
      bf16x8 bfrag = *(const bf16x8*)&Ks[(w * 16 + lr) * 136 + ks * 32 + lq * 8];
#pragma unroll
      for (int mi = 0; mi < 4; mi++) {
        bf16x8 afrag = *(const bf16x8*)&Qs[(mi * 16 + lr) * 136 + ks * 32 + lq * 8];
        sacc[mi] = mfma16(afrag, bfrag, sacc[mi]);
      }
    }
    float s[4][4], pm[4][4];
#pragma unroll
    for (int mi = 0; mi < 4; mi++) {
#pragma unroll
      for (int r = 0; r < 4; r++) {
        float v = sacc[mi][r] * sscale;
        if (j == qi) {
          int colg = w * 16 + lr, rowg = mi * 16 + lq * 4 + r;
          if (colg > rowg) v = -INFINITY;
        }
        s[mi][r] = v;
        float mv = v;
        mv = fmaxf(mv, __shfl_xor(mv, 1));
        mv = fmaxf(mv, __shfl_xor(mv, 2));
        mv = fmaxf(mv, __shfl_xor(mv, 4));
        mv = fmaxf(mv, __shfl_xor(mv, 8));
        pm[mi][r] = mv;
      }
    }
    if (lr == 0) {
#pragma unroll
      for (int mi = 0; mi < 4; mi++)
#pragma unroll
        for (int r = 0; r < 4; r++)
          redm[w * 64 + mi * 16 + lq * 4 + r] = pm[mi][r];
    }
    __syncthreads();
    float alpha[4][4], mnew[4][4], psum[4][4];
#pragma unroll
    for (int mi = 0; mi < 4; mi++) {
#pragma unroll
      for (int r = 0; r < 4; r++) {
        int row = mi * 16 + lq * 4 + r;
        float mo = mL[row];
        float mj = fmaxf(fmaxf(redm[row], redm[64 + row]),
                         fmaxf(redm[128 + row], redm[192 + row]));
        float mn = fmaxf(mo, mj);
        mnew[mi][r] = mn;
        alpha[mi][r] = __expf(mo - mn);  // -inf -> 0
        float p = __expf(s[mi][r] - mn);
        Ps[row * 72 + w * 16 + lr] = f2bf(p);
        float ps = p;
        ps += __shfl_xor(ps, 1);
        ps += __shfl_xor(ps, 2);
        ps += __shfl_xor(ps, 4);
        ps += __shfl_xor(ps, 8);
        psum[mi][r] = ps;
      }
    }
    if (lr == 0) {
#pragma unroll
      for (int mi = 0; mi < 4; mi++)
#pragma unroll
        for (int r = 0; r < 4; r++)
          reds[w * 64 + mi * 16 + lq * 4 + r] = psum[mi][r];
    }
    // rescale O accumulator by alpha (row layout matches C/D layout)
#pragma unroll
    for (int mi = 0; mi < 4; mi++)
#pragma unroll
      for (int ei = 0; ei < 4; ei++)
#pragma unroll
        for (int r = 0; r < 4; r++)
          acc[mi][ei][r] *= alpha[mi][r];
    __syncthreads();  // Ps/reds visible; everyone done reading mL
    if (w == 0 && lr == 0) {
#pragma unroll
      for (int mi = 0; mi < 4; mi++)
#pragma unroll
        for (int r = 0; r < 4; r++) {
          int row = mi * 16 + lq * 4 + r;
          lL[row] = lL[row] * alpha[mi][r] +
                    reds[row] + reds[64 + row] + reds[128 + row] + reds[192 + row];
          mL[row] = mnew[mi][r];
        }
    }
    // O += P @ V  (K=64 -> 2 MFMA k-steps)
#pragma unroll
    for (int ks = 0; ks < 2; ks++) {
      bf16x8 pa[4], vb[4];
#pragma unroll
      for (int mi = 0; mi < 4; mi++)
        pa[mi] = *(const bf16x8*)&Ps[(mi * 16 + lr) * 72 + ks * 32 + lq * 8];
#pragma unroll
      for (int ei = 0; ei < 4; ei++)
        vb[ei] = *(const bf16x8*)&Vs[(w * 64 + ei * 16 + lr) * 72 + ks * 32 + lq * 8];
#pragma unroll
      for (int mi = 0; mi < 4; mi++)
#pragma unroll
        for (int ei = 0; ei < 4; ei++)
          acc[mi][ei] = mfma16(pa[mi], vb[ei], acc[mi][ei]);
    }
  }
  __syncthreads();
  // epilogue: o12[c][b][t][h][e] = acc / l
  float* op = o12 + (size_t)c * (2ull * 2048 * 8 * 256) +
              ((size_t)(b * 2048 + q0) * 8 + h) * 256;
#pragma unroll
  for (int mi = 0; mi < 4; mi++) {
#pragma unroll
    for (int r = 0; r < 4; r++) {
      int row = mi * 16 + lq * 4 + r;
      float inv = 1.0f / lL[row];
#pragma unroll
      for (int ei = 0; ei < 4; ei++)
        op[(size_t)row * 2048 + w * 64 + ei * 16 + lr] = acc[mi][ei][r] * inv;
    }
  }
}

// --------------------------- combine + RMSNorm -----------------------------
// One block per (b,t,h) group of 256 elems: o = o1 - lam*o2, RMSNorm(256),
// * g * (1-LAMBDA_INIT), cast bf16 into ob[4096][2048].
__global__ void combine_kernel(const float* __restrict__ o12, const float* __restrict__ lamp,
                               const float* __restrict__ g, u16* __restrict__ ob) {
  __shared__ float red[4];
  int t = threadIdx.x;
  int grp = blockIdx.x;  // (b*2048+tt)*8 + h
  size_t idx = (size_t)grp * 256 + t;
  const size_t comp = 2ull * 2048 * 8 * 256;
  float lam = lamp[0];
  float v = o12[idx] - lam * o12[idx + comp];
  float ss = v * v;
  ss += __shfl_xor(ss, 1);
  ss += __shfl_xor(ss, 2);
  ss += __shfl_xor(ss, 4);
  ss += __shfl_xor(ss, 8);
  ss += __shfl_xor(ss, 16);
  ss += __shfl_xor(ss, 32);
  if ((t & 63) == 0) red[t >> 6] = ss;
  __syncthreads();
  float tot = red[0] + red[1] + red[2] + red[3];
  float scale = rsqrtf(tot * (1.0f / 256.0f) + 1e-5f) * (1.0f - LAMBDA_INIT);
  ob[(size_t)(grp >> 3) * 2048 + (grp & 7) * 256 + t] = f2bf(v * scale * g[t]);
}

// ---------------------------------------------------------------------------

extern "C" void kernel_launch(void* const* d_in, const int* in_sizes, int n_in,
                              void* d_out, int out_size, void* d_ws, size_t ws_size,
                              hipStream_t stream) {
  const float* x   = (const float*)d_in[0];
  const float* Wq  = (const float*)d_in[1];
  const float* Wk  = (const float*)d_in[2];
  const float* Wv  = (const float*)d_in[3];
  const float* Wo  = (const float*)d_in[4];
  const float* lq1 = (const float*)d_in[5];
  const float* lk1 = (const float*)d_in[6];
  const float* lq2 = (const float*)d_in[7];
  const float* lk2 = (const float*)d_in[8];
  const float* g   = (const float*)d_in[9];

  char* ws = (char*)d_ws;
  u16* xb    = (u16*)(ws);
  u16* Wtq   = (u16*)(ws + 16777216);
  u16* Wtk   = (u16*)(ws + 25165824);
  u16* Wtv   = (u16*)(ws + 33554432);
  u16* Wto   = (u16*)(ws + 41943040);
  u16* Qb    = (u16*)(ws + 50331648);
  u16* Kb    = (u16*)(ws + 67108864);
  u16* Vb    = (u16*)(ws + 83886080);
  u16* Vtb   = (u16*)(ws + 100663296);
  float* o12 = (float*)(ws + 117440512);
  u16* ob    = (u16*)(ws + 184549376);
  float* lamp = (float*)(ws + 201326592);

  cast_x_kernel<<<8192, 256, 0, stream>>>(x, xb, 2097152);
  dim3 tb(32, 8), tg(64, 64);
  transpose_w_kernel<<<tg, tb, 0, stream>>>(Wq, Wtq);
  transpose_w_kernel<<<tg, tb, 0, stream>>>(Wk, Wtk);
  transpose_w_kernel<<<tg, tb, 0, stream>>>(Wv, Wtv);
  transpose_w_kernel<<<tg, tb, 0, stream>>>(Wo, Wto);
  lam_kernel<<<1, 64, 0, stream>>>(lq1, lk1, lq2, lk2, lamp);

  dim3 gg(16, 32);  // (N/128, M/128)
  gemm_bt_kernel<1><<<gg, 256, 0, stream>>>(xb, Wtq, Qb, 4096, 2048, 2048);
  gemm_bt_kernel<1><<<gg, 256, 0, stream>>>(xb, Wtk, Kb, 4096, 2048, 2048);
  gemm_bt_kernel<1><<<gg, 256, 0, stream>>>(xb, Wtv, Vb, 4096, 2048, 2048);
  transpose_v_kernel<<<dim3(64, 64, 2), tb, 0, stream>>>(Vb, Vtb);

  flash_diff_kernel<<<dim3(32, 16, 2), 256, 0, stream>>>(Qb, Kb, Vtb, o12);
  combine_kernel<<<32768, 256, 0, stream>>>(o12, lamp, g, ob);
  gemm_bt_kernel<0><<<gg, 256, 0, stream>>>(ob, Wto, (float*)d_out, 4096, 2048, 2048);
}

// Round 2
// 493.892 us; speedup vs baseline: 1.9665x; 1.9665x over previous
//
#include <hip/hip_runtime.h>
#include <stdint.h>
#include <math.h>

// ---------------------------------------------------------------------------
// MultiheadSdpaDiff3 round 2.
// ws layout (bytes):
//   xb   @ 0          : 16777216   (x as bf16 [4096][2048])
//   Wtq  @ 16777216   : 8388608    (Wq^T bf16 [N][K])
//   Wtk  @ 25165824   : 8388608
//   Wtv  @ 33554432   : 8388608
//   Wto  @ 41943040   : 8388608
//   Qb   @ 50331648   : 16777216   (bf16 [4096][2048])
//   Kb   @ 67108864   : 16777216
//   Vt   @ 83886080   : 16777216   (bf16 [2048 e][4096 bt] = V^T, from gemm)
//   o12b @ 100663296  : 33554432   (bf16 [c][bt][h*256+e])
//   ob   @ 134217728  : 16777216   (combined+rmsnormed bf16 [4096][2048])
//   lam  @ 150994944  : 256
// ---------------------------------------------------------------------------

typedef unsigned short u16;
typedef short bf16x8 __attribute__((ext_vector_type(8)));
typedef float f32x4 __attribute__((ext_vector_type(4)));

typedef uint32_t __attribute__((address_space(1))) as1_u32;
typedef uint32_t __attribute__((address_space(3))) as3_u32;

#define LAMBDA_INIT 0.78360576653162453f

__device__ __forceinline__ u16 f2bf(float f) {
  uint32_t u = __float_as_uint(f);
  u += 0x7FFFu + ((u >> 16) & 1u);   // RNE
  return (u16)(u >> 16);
}
__device__ __forceinline__ float bf2f(u16 v) {
  return __uint_as_float(((uint32_t)v) << 16);
}

__device__ __forceinline__ void async16(u16* lds, const u16* g) {
  __builtin_amdgcn_global_load_lds((const as1_u32*)(uintptr_t)g,
                                   (as3_u32*)(uint32_t)(uintptr_t)lds, 16, 0, 0);
}

__device__ __forceinline__ f32x4 mfma16(bf16x8 a, bf16x8 b, f32x4 c) {
  return __builtin_amdgcn_mfma_f32_16x16x32_bf16(a, b, c, 0, 0, 0);
}

// --------------------------- prep kernels ----------------------------------

__global__ void cast_x_kernel(const float* __restrict__ x, u16* __restrict__ xb, int n4) {
  int i = blockIdx.x * 256 + threadIdx.x;
  if (i < n4) {
    float4 v = ((const float4*)x)[i];
    ushort4 o;
    o.x = f2bf(v.x); o.y = f2bf(v.y); o.z = f2bf(v.z); o.w = f2bf(v.w);
    ((ushort4*)xb)[i] = o;
  }
}

// Wt[n][k] = bf16(W[k][n]); W is [2048][2048] fp32.
__global__ void transpose_w_kernel(const float* __restrict__ W, u16* __restrict__ Wt) {
  __shared__ float tile[32][33];
  int tx = threadIdx.x, ty = threadIdx.y;
  int c0 = blockIdx.x * 32, r0 = blockIdx.y * 32;
#pragma unroll
  for (int i = 0; i < 32; i += 8)
    tile[ty + i][tx] = W[(size_t)(r0 + ty + i) * 2048 + c0 + tx];
  __syncthreads();
#pragma unroll
  for (int i = 0; i < 32; i += 8)
    Wt[(size_t)(c0 + ty + i) * 2048 + r0 + tx] = f2bf(tile[tx][ty + i]);
}

__global__ void lam_kernel(const float* __restrict__ lq1, const float* __restrict__ lk1,
                           const float* __restrict__ lq2, const float* __restrict__ lk2,
                           float* __restrict__ out) {
  int L = threadIdx.x;  // 64 threads
  float d1 = lq1[L] * lk1[L] + lq1[L + 64] * lk1[L + 64];
  float d2 = lq2[L] * lk2[L] + lq2[L + 64] * lk2[L + 64];
#pragma unroll
  for (int m = 1; m < 64; m <<= 1) {
    d1 += __shfl_xor(d1, m);
    d2 += __shfl_xor(d2, m);
  }
  if (L == 0) out[0] = __expf(d1) - __expf(d2) + LAMBDA_INIT;
}

// --------------------------- GEMM (m97 structure) --------------------------
// C[M,N] = A[M,K] @ Bt[N,K]^T ; A,Bt bf16 row-major; 128x128 tile, BK=32.
template <int OUT_BF16>
__global__ __launch_bounds__(256, 2) void gemm_bt_kernel(const u16* __restrict__ A,
                                                         const u16* __restrict__ Bt,
                                                         void* __restrict__ Cout,
                                                         int M, int N, int K) {
  __shared__ __attribute__((aligned(16))) u16 As[128 * 32];
  __shared__ __attribute__((aligned(16))) u16 Bs[128 * 32];
  int t = threadIdx.x;
  int lane = t & 63, w = t >> 6;
  int lr = lane & 15, lq = lane >> 4;
  int m0 = blockIdx.y * 128, n0 = blockIdx.x * 128;
  int wm = (w >> 1) * 64, wn = (w & 1) * 64;
  const u16* Ab = A + (size_t)m0 * K;
  const u16* Bb = Bt + (size_t)n0 * K;
  f32x4 acc[4][4] = {};
  int r0 = t >> 2;
  int kc0 = (t & 3) * 8;

  for (int k0 = 0; k0 < K; k0 += 32) {
    __syncthreads();
    async16(&As[t * 8], Ab + (size_t)r0 * K + k0 + kc0);
    async16(&Bs[t * 8], Bb + (size_t)r0 * K + k0 + kc0);
    async16(&As[(256 + t) * 8], Ab + (size_t)(64 + r0) * K + k0 + kc0);
    async16(&Bs[(256 + t) * 8], Bb + (size_t)(64 + r0) * K + k0 + kc0);
    __syncthreads();
    bf16x8 a[4], b[4];
#pragma unroll
    for (int mi = 0; mi < 4; mi++)
      a[mi] = *(const bf16x8*)&As[(wm + mi * 16 + lr) * 32 + lq * 8];
#pragma unroll
    for (int ni = 0; ni < 4; ni++)
      b[ni] = *(const bf16x8*)&Bs[(wn + ni * 16 + lr) * 32 + lq * 8];
#pragma unroll
    for (int mi = 0; mi < 4; mi++)
#pragma unroll
      for (int ni = 0; ni < 4; ni++)
        acc[mi][ni] = mfma16(a[mi], b[ni], acc[mi][ni]);
  }
#pragma unroll
  for (int mi = 0; mi < 4; mi++) {
#pragma unroll
    for (int ni = 0; ni < 4; ni++) {
#pragma unroll
      for (int r = 0; r < 4; r++) {
        int row = m0 + wm + mi * 16 + lq * 4 + r;
        int col = n0 + wn + ni * 16 + lr;
        if (OUT_BF16)
          ((u16*)Cout)[(size_t)row * N + col] = f2bf(acc[mi][ni][r]);
        else
          ((float*)Cout)[(size_t)row * N + col] = acc[mi][ni][r];
      }
    }
  }
}

// --------------------------- flash attention -------------------------------
// Grid (pair 16, bh 16, c 2). Block 256 thr = 4 waves; wave w owns Q-rows
// [w*16, w*16+16) of the current 64-row q-tile, full e range (256).
// Block runs q-tile qi = pair, then 31-pair: uniform 33 j-steps per block.
// Softmax state fully in registers (4 rows/lane). Q fragments in registers.
// LDS: K tile [64][136], V^T tile [256][72], P per-wave [16][72] -> 62976 B
// -> 2 blocks/CU (8 waves).
__global__ __launch_bounds__(256, 2) void flash_diff_kernel(const u16* __restrict__ Qb,
                                                            const u16* __restrict__ Kb,
                                                            const u16* __restrict__ Vt,
                                                            u16* __restrict__ o12b) {
  __shared__ __attribute__((aligned(16))) u16 Ks[64 * 136];   // stride 272B (2-way)
  __shared__ __attribute__((aligned(16))) u16 Vs[256 * 72];   // stride 144B (2-way)
  __shared__ __attribute__((aligned(16))) u16 Ps[4][16 * 72]; // per-wave private

  int t = threadIdx.x;
  int lane = t & 63, w = t >> 6, lr = lane & 15, lq = lane >> 4;
  int pairI = blockIdx.x, bh = blockIdx.y, c = blockIdx.z;
  int b = bh >> 3, h = bh & 7;

  const u16* Qp = Qb + (size_t)b * 2048 * 2048 + h * 256 + c * 128;
  const u16* Kp = Kb + (size_t)b * 2048 * 2048 + h * 256 + c * 128;
  const u16* Vp = Vt + (size_t)(h * 256) * 4096 + b * 2048;
  u16* Op = o12b + (size_t)c * (4096ull * 2048) + (size_t)b * 2048 * 2048 + h * 256;

  const float sscale = 0.088388347648318447f;  // 1/sqrt(128)

#pragma unroll 1
  for (int phase = 0; phase < 2; phase++) {
    int qi = phase ? (31 - pairI) : pairI;
    int q0 = qi * 64;

    // Q fragments in registers (A-operand layout: m=lr, k=ks*32+lq*8)
    bf16x8 qa[4];
#pragma unroll
    for (int ks = 0; ks < 4; ks++)
      qa[ks] = *(const bf16x8*)&Qp[(size_t)(q0 + w * 16 + lr) * 2048 + ks * 32 + lq * 8];

    f32x4 acc[16] = {};
    float m_[4] = {-INFINITY, -INFINITY, -INFINITY, -INFINITY};
    float l_[4] = {};

#pragma unroll 1
    for (int j = 0; j <= qi; j++) {
      __syncthreads();
      // stage K tile [64 rows][128 e-cols of this c]
#pragma unroll
      for (int i = 0; i < 4; i++) {
        int chunk = i * 256 + t, row = chunk >> 4, cc = (chunk & 15) * 8;
        *(uint4*)&Ks[row * 136 + cc] =
            *(const uint4*)&Kp[(size_t)(j * 64 + row) * 2048 + cc];
      }
      // stage V^T tile [256 e][64 n]
#pragma unroll
      for (int i = 0; i < 8; i++) {
        int chunk = i * 256 + t, e = chunk >> 3, cc = (chunk & 7) * 8;
        *(uint4*)&Vs[e * 72 + cc] =
            *(const uint4*)&Vp[(size_t)e * 4096 + j * 64 + cc];
      }
      __syncthreads();

      // S = Q K^T : wave computes 16 rows x 64 cols
      f32x4 sacc[4] = {};
#pragma unroll
      for (int ks = 0; ks < 4; ks++) {
#pragma unroll
        for (int ni = 0; ni < 4; ni++) {
          bf16x8 kb = *(const bf16x8*)&Ks[(ni * 16 + lr) * 136 + ks * 32 + lq * 8];
          sacc[ni] = mfma16(qa[ks], kb, sacc[ni]);
        }
      }

      float sc[4][4];  // [ni][r]
#pragma unroll
      for (int ni = 0; ni < 4; ni++) {
#pragma unroll
        for (int r = 0; r < 4; r++) {
          float v = sacc[ni][r] * sscale;
          if (j == qi) {
            int colg = j * 64 + ni * 16 + lr;
            int rowg = q0 + w * 16 + lq * 4 + r;
            if (colg > rowg) v = -INFINITY;
          }
          sc[ni][r] = v;
        }
      }
      // online softmax, in-register (4 rows per lane, replicated across lr)
#pragma unroll
      for (int r = 0; r < 4; r++) {
        float mv = fmaxf(fmaxf(sc[0][r], sc[1][r]), fmaxf(sc[2][r], sc[3][r]));
        mv = fmaxf(mv, __shfl_xor(mv, 1));
        mv = fmaxf(mv, __shfl_xor(mv, 2));
        mv = fmaxf(mv, __shfl_xor(mv, 4));
        mv = fmaxf(mv, __shfl_xor(mv, 8));
        float mn = fmaxf(m_[r], mv);
        float al = __expf(m_[r] - mn);
        float ps = 0.0f;
#pragma unroll
        for (int ni = 0; ni < 4; ni++) {
          float p = __expf(sc[ni][r] - mn);
          Ps[w][(lq * 4 + r) * 72 + ni * 16 + lr] = f2bf(p);
          ps += p;
        }
        ps += __shfl_xor(ps, 1);
        ps += __shfl_xor(ps, 2);
        ps += __shfl_xor(ps, 4);
        ps += __shfl_xor(ps, 8);
        l_[r] = l_[r] * al + ps;
        m_[r] = mn;
#pragma unroll
        for (int ei = 0; ei < 16; ei++) acc[ei][r] *= al;
      }

      // O += P @ V   (wave-private Ps; same-wave write->read, lgkmcnt only)
#pragma unroll
      for (int ks = 0; ks < 2; ks++) {
        bf16x8 pa = *(const bf16x8*)&Ps[w][lr * 72 + ks * 32 + lq * 8];
#pragma unroll
        for (int ei = 0; ei < 16; ei++) {
          bf16x8 vb = *(const bf16x8*)&Vs[(ei * 16 + lr) * 72 + ks * 32 + lq * 8];
          acc[ei] = mfma16(pa, vb, acc[ei]);
        }
      }
    }

    // epilogue: o12b[c][b*2048+row][h*256+e] = acc/l  (bf16)
#pragma unroll
    for (int r = 0; r < 4; r++) {
      float inv = 1.0f / l_[r];
      int row = q0 + w * 16 + lq * 4 + r;
#pragma unroll
      for (int ei = 0; ei < 16; ei++)
        Op[(size_t)row * 2048 + ei * 16 + lr] = f2bf(acc[ei][r] * inv);
    }
  }
}

// --------------------------- combine + RMSNorm -----------------------------
__global__ void combine_kernel(const u16* __restrict__ o12b, const float* __restrict__ lamp,
                               const float* __restrict__ g, u16* __restrict__ ob) {
  __shared__ float red[4];
  int t = threadIdx.x;
  int grp = blockIdx.x;  // (b*2048+tt)*8 + h
  size_t idx = (size_t)grp * 256 + t;
  const size_t comp = 4096ull * 2048;
  float lam = lamp[0];
  float v = bf2f(o12b[idx]) - lam * bf2f(o12b[idx + comp]);
  float ss = v * v;
  ss += __shfl_xor(ss, 1);
  ss += __shfl_xor(ss, 2);
  ss += __shfl_xor(ss, 4);
  ss += __shfl_xor(ss, 8);
  ss += __shfl_xor(ss, 16);
  ss += __shfl_xor(ss, 32);
  if ((t & 63) == 0) red[t >> 6] = ss;
  __syncthreads();
  float tot = red[0] + red[1] + red[2] + red[3];
  float scale = rsqrtf(tot * (1.0f / 256.0f) + 1e-5f) * (1.0f - LAMBDA_INIT);
  ob[(size_t)(grp >> 3) * 2048 + (grp & 7) * 256 + t] = f2bf(v * scale * g[t]);
}

// ---------------------------------------------------------------------------

extern "C" void kernel_launch(void* const* d_in, const int* in_sizes, int n_in,
                              void* d_out, int out_size, void* d_ws, size_t ws_size,
                              hipStream_t stream) {
  const float* x   = (const float*)d_in[0];
  const float* Wq  = (const float*)d_in[1];
  const float* Wk  = (const float*)d_in[2];
  const float* Wv  = (const float*)d_in[3];
  const float* Wo  = (const float*)d_in[4];
  const float* lq1 = (const float*)d_in[5];
  const float* lk1 = (const float*)d_in[6];
  const float* lq2 = (const float*)d_in[7];
  const float* lk2 = (const float*)d_in[8];
  const float* g   = (const float*)d_in[9];

  char* ws = (char*)d_ws;
  u16* xb    = (u16*)(ws);
  u16* Wtq   = (u16*)(ws + 16777216);
  u16* Wtk   = (u16*)(ws + 25165824);
  u16* Wtv   = (u16*)(ws + 33554432);
  u16* Wto   = (u16*)(ws + 41943040);
  u16* Qb    = (u16*)(ws + 50331648);
  u16* Kb    = (u16*)(ws + 67108864);
  u16* Vt    = (u16*)(ws + 83886080);
  u16* o12b  = (u16*)(ws + 100663296);
  u16* ob    = (u16*)(ws + 134217728);
  float* lamp = (float*)(ws + 150994944);

  cast_x_kernel<<<8192, 256, 0, stream>>>(x, xb, 2097152);
  dim3 tb(32, 8), tg(64, 64);
  transpose_w_kernel<<<tg, tb, 0, stream>>>(Wq, Wtq);
  transpose_w_kernel<<<tg, tb, 0, stream>>>(Wk, Wtk);
  transpose_w_kernel<<<tg, tb, 0, stream>>>(Wv, Wtv);
  transpose_w_kernel<<<tg, tb, 0, stream>>>(Wo, Wto);
  lam_kernel<<<1, 64, 0, stream>>>(lq1, lk1, lq2, lk2, lamp);

  // Q = x@Wq, K = x@Wk : [4096][2048]
  gemm_bt_kernel<1><<<dim3(16, 32), 256, 0, stream>>>(xb, Wtq, Qb, 4096, 2048, 2048);
  gemm_bt_kernel<1><<<dim3(16, 32), 256, 0, stream>>>(xb, Wtk, Kb, 4096, 2048, 2048);
  // V^T directly: C[e][bt] = sum_k Wv[k][e] x[bt][k]  (M=2048, N=4096)
  gemm_bt_kernel<1><<<dim3(32, 16), 256, 0, stream>>>(Wtv, xb, Vt, 2048, 4096, 2048);

  flash_diff_kernel<<<dim3(16, 16, 2), 256, 0, stream>>>(Qb, Kb, Vt, o12b);
  combine_kernel<<<32768, 256, 0, stream>>>(o12b, lamp, g, ob);
  gemm_bt_kernel<0><<<dim3(16, 32), 256, 0, stream>>>(ob, Wto, (float*)d_out, 4096, 2048, 2048);
}

// Round 3
// 493.118 us; speedup vs baseline: 1.9696x; 1.0016x over previous
//
#include <hip/hip_runtime.h>
#include <stdint.h>
#include <math.h>

// ---------------------------------------------------------------------------
// MultiheadSdpaDiff3 round 3.
// ws layout (bytes):
//   xb   @ 0          : 16777216   (x as bf16 [4096][2048])
//   Wtq  @ 16777216   : 8388608    (Wq^T bf16 [N][K])
//   Wtk  @ 25165824   : 8388608    (contiguous after Wtq -> merged QK gemm)
//   Wtv  @ 33554432   : 8388608
//   Wto  @ 41943040   : 8388608
//   QKb  @ 50331648   : 33554432   (bf16 [4096][4096]: cols 0-2047 Q, 2048-4095 K)
//   Vt   @ 83886080   : 16777216   (bf16 [2048 e][4096 bt] = V^T, from gemm)
//   o12b @ 100663296  : 33554432   (bf16 [c][bt][h*256+e])
//   ob   @ 134217728  : 16777216   (combined+rmsnormed bf16 [4096][2048])
//   lam  @ 150994944  : 256
// ---------------------------------------------------------------------------

typedef unsigned short u16;
typedef short bf16x8 __attribute__((ext_vector_type(8)));
typedef float f32x4 __attribute__((ext_vector_type(4)));

typedef uint32_t __attribute__((address_space(1))) as1_u32;
typedef uint32_t __attribute__((address_space(3))) as3_u32;

#define LAMBDA_INIT 0.78360576653162453f

__device__ __forceinline__ u16 f2bf(float f) {
  uint32_t u = __float_as_uint(f);
  u += 0x7FFFu + ((u >> 16) & 1u);   // RNE
  return (u16)(u >> 16);
}
__device__ __forceinline__ float bf2f(u16 v) {
  return __uint_as_float(((uint32_t)v) << 16);
}

__device__ __forceinline__ void async16(u16* lds, const u16* g) {
  __builtin_amdgcn_global_load_lds((const as1_u32*)(uintptr_t)g,
                                   (as3_u32*)(uint32_t)(uintptr_t)lds, 16, 0, 0);
}

__device__ __forceinline__ f32x4 mfma16(bf16x8 a, bf16x8 b, f32x4 c) {
  return __builtin_amdgcn_mfma_f32_16x16x32_bf16(a, b, c, 0, 0, 0);
}

// --------------------------- prep kernels ----------------------------------

__global__ void cast_x_kernel(const float* __restrict__ x, u16* __restrict__ xb, int n4) {
  int i = blockIdx.x * 256 + threadIdx.x;
  if (i < n4) {
    float4 v = ((const float4*)x)[i];
    ushort4 o;
    o.x = f2bf(v.x); o.y = f2bf(v.y); o.z = f2bf(v.z); o.w = f2bf(v.w);
    ((ushort4*)xb)[i] = o;
  }
}

// Wt[n][k] = bf16(W[k][n]); W is [2048][2048] fp32.
__global__ void transpose_w_kernel(const float* __restrict__ W, u16* __restrict__ Wt) {
  __shared__ float tile[32][33];
  int tx = threadIdx.x, ty = threadIdx.y;
  int c0 = blockIdx.x * 32, r0 = blockIdx.y * 32;
#pragma unroll
  for (int i = 0; i < 32; i += 8)
    tile[ty + i][tx] = W[(size_t)(r0 + ty + i) * 2048 + c0 + tx];
  __syncthreads();
#pragma unroll
  for (int i = 0; i < 32; i += 8)
    Wt[(size_t)(c0 + ty + i) * 2048 + r0 + tx] = f2bf(tile[tx][ty + i]);
}

__global__ void lam_kernel(const float* __restrict__ lq1, const float* __restrict__ lk1,
                           const float* __restrict__ lq2, const float* __restrict__ lk2,
                           float* __restrict__ out) {
  int L = threadIdx.x;  // 64 threads
  float d1 = lq1[L] * lk1[L] + lq1[L + 64] * lk1[L + 64];
  float d2 = lq2[L] * lk2[L] + lq2[L + 64] * lk2[L + 64];
#pragma unroll
  for (int m = 1; m < 64; m <<= 1) {
    d1 += __shfl_xor(d1, m);
    d2 += __shfl_xor(d2, m);
  }
  if (L == 0) out[0] = __expf(d1) - __expf(d2) + LAMBDA_INIT;
}

// --------------------------- GEMM (m97 structure) --------------------------
template <int OUT_BF16>
__global__ __launch_bounds__(256, 2) void gemm_bt_kernel(const u16* __restrict__ A,
                                                         const u16* __restrict__ Bt,
                                                         void* __restrict__ Cout,
                                                         int M, int N, int K) {
  __shared__ __attribute__((aligned(16))) u16 As[128 * 32];
  __shared__ __attribute__((aligned(16))) u16 Bs[128 * 32];
  int t = threadIdx.x;
  int lane = t & 63, w = t >> 6;
  int lr = lane & 15, lq = lane >> 4;
  int m0 = blockIdx.y * 128, n0 = blockIdx.x * 128;
  int wm = (w >> 1) * 64, wn = (w & 1) * 64;
  const u16* Ab = A + (size_t)m0 * K;
  const u16* Bb = Bt + (size_t)n0 * K;
  f32x4 acc[4][4] = {};
  int r0 = t >> 2;
  int kc0 = (t & 3) * 8;

  for (int k0 = 0; k0 < K; k0 += 32) {
    __syncthreads();
    async16(&As[t * 8], Ab + (size_t)r0 * K + k0 + kc0);
    async16(&Bs[t * 8], Bb + (size_t)r0 * K + k0 + kc0);
    async16(&As[(256 + t) * 8], Ab + (size_t)(64 + r0) * K + k0 + kc0);
    async16(&Bs[(256 + t) * 8], Bb + (size_t)(64 + r0) * K + k0 + kc0);
    __syncthreads();
    bf16x8 a[4], b[4];
#pragma unroll
    for (int mi = 0; mi < 4; mi++)
      a[mi] = *(const bf16x8*)&As[(wm + mi * 16 + lr) * 32 + lq * 8];
#pragma unroll
    for (int ni = 0; ni < 4; ni++)
      b[ni] = *(const bf16x8*)&Bs[(wn + ni * 16 + lr) * 32 + lq * 8];
#pragma unroll
    for (int mi = 0; mi < 4; mi++)
#pragma unroll
      for (int ni = 0; ni < 4; ni++)
        acc[mi][ni] = mfma16(a[mi], b[ni], acc[mi][ni]);
  }
#pragma unroll
  for (int mi = 0; mi < 4; mi++) {
#pragma unroll
    for (int ni = 0; ni < 4; ni++) {
#pragma unroll
      for (int r = 0; r < 4; r++) {
        int row = m0 + wm + mi * 16 + lq * 4 + r;
        int col = n0 + wn + ni * 16 + lr;
        if (OUT_BF16)
          ((u16*)Cout)[(size_t)row * N + col] = f2bf(acc[mi][ni][r]);
        else
          ((float*)Cout)[(size_t)row * N + col] = acc[mi][ni][r];
      }
    }
  }
}

// --------------------------- flash attention -------------------------------
// Grid: 512 blocks 1D, XCD-affine decode. Block = 256 thr = 4 waves; wave w
// owns Q-rows [w*16,w*16+16) of a 64-row q-tile, all 256 V-cols. Block runs
// q-tile qi=pair then 31-pair (uniform 68 32-row j-steps). Double-buffered
// K/V staging via global_load_lds; even/odd steps use distinct LDS arrays.
// K LDS layout: [32 rows][16 granules of 16B], granule XOR-swizzled by row&7.

struct FlashCtx {
  const u16* Qbase;
  const u16* Kbase;
  const u16* Vbase;
  int t, lane, w, lr, lq;
};

__device__ __forceinline__ void stage_kv(const FlashCtx& cx, int jc,
                                         u16* KsN, u16* VsN) {
#pragma unroll
  for (int i = 0; i < 2; i++) {
    int q = cx.t + i * 256;
    int row = q >> 4, gp = q & 15;
    int gg = (gp & 8) | ((gp & 7) ^ (row & 7));
    async16(&KsN[q * 8], cx.Kbase + (size_t)(jc + row) * 4096 + gg * 8);
  }
#pragma unroll
  for (int i = 0; i < 4; i++) {
    int q = cx.t + i * 256;
    int e = q >> 2, gp = q & 3;
    async16(&VsN[q * 8], cx.Vbase + (size_t)e * 4096 + jc + gp * 8);
  }
}

__device__ __forceinline__ void flash_step(const FlashCtx& cx, const bf16x8* qa,
                                           int jc, int njc, int q0,
                                           const u16* KsC, const u16* VsC,
                                           u16* KsN, u16* VsN, u16* PsW,
                                           f32x4* acc, float* m_, float* l_) {
  __syncthreads();              // joins prev compute; drains DMA for KsC/VsC
  if (njc >= 0) stage_kv(cx, njc, KsN, VsN);   // overlaps with compute below

  bool active = (jc <= q0 + cx.w * 16 + 15);
  if (!active) return;
  const float sscale = 0.088388347648318447f;  // 1/sqrt(128)
  int lr = cx.lr, lq = cx.lq;

  // S = Q K^T : 16 rows x 32 cols per wave
  f32x4 sacc[2] = {};
#pragma unroll
  for (int ks = 0; ks < 4; ks++) {
#pragma unroll
    for (int ni = 0; ni < 2; ni++) {
      int row = ni * 16 + lr;
      int g = ks * 4 + lq;
      int gp = (g & 8) | ((g & 7) ^ (row & 7));
      bf16x8 kb = *(const bf16x8*)&KsC[row * 128 + gp * 8];
      sacc[ni] = mfma16(qa[ks], kb, sacc[ni]);
    }
  }

  float al[4];
  bool nochange = true;
#pragma unroll
  for (int r = 0; r < 4; r++) {
    float s0 = sacc[0][r] * sscale, s1 = sacc[1][r] * sscale;
    if (jc >= q0) {  // diagonal tiles only
      int rowg = q0 + cx.w * 16 + lq * 4 + r;
      if (jc + lr > rowg) s0 = -INFINITY;
      if (jc + 16 + lr > rowg) s1 = -INFINITY;
    }
    float mv = fmaxf(s0, s1);
    mv = fmaxf(mv, __shfl_xor(mv, 1));
    mv = fmaxf(mv, __shfl_xor(mv, 2));
    mv = fmaxf(mv, __shfl_xor(mv, 4));
    mv = fmaxf(mv, __shfl_xor(mv, 8));
    float mo = m_[r];
    float mn = fmaxf(mo, mv);
    float a = __expf(mo - mn);
    al[r] = a;
    float p0 = __expf(s0 - mn), p1 = __expf(s1 - mn);
    PsW[(lq * 4 + r) * 40 + lr] = f2bf(p0);
    PsW[(lq * 4 + r) * 40 + 16 + lr] = f2bf(p1);
    float ps = p0 + p1;
    ps += __shfl_xor(ps, 1);
    ps += __shfl_xor(ps, 2);
    ps += __shfl_xor(ps, 4);
    ps += __shfl_xor(ps, 8);
    l_[r] = l_[r] * a + ps;
    m_[r] = mn;
    nochange = nochange && (a == 1.0f);
  }
  if (!__all(nochange ? 1 : 0)) {
#pragma unroll
    for (int ei = 0; ei < 16; ei++)
#pragma unroll
      for (int r = 0; r < 4; r++) acc[ei][r] *= al[r];
  }
  // O += P @ V  (P wave-private in LDS; same-wave write->read)
  bf16x8 pa = *(const bf16x8*)&PsW[lr * 40 + lq * 8];
#pragma unroll
  for (int ei = 0; ei < 16; ei++) {
    bf16x8 vb = *(const bf16x8*)&VsC[(ei * 16 + lr) * 32 + lq * 8];
    acc[ei] = mfma16(pa, vb, acc[ei]);
  }
}

__global__ __launch_bounds__(256, 2) void flash_diff_kernel(const u16* __restrict__ QKb,
                                                            const u16* __restrict__ Vt,
                                                            u16* __restrict__ o12b) {
  __shared__ __attribute__((aligned(16))) u16 Ks0[32 * 128];
  __shared__ __attribute__((aligned(16))) u16 Ks1[32 * 128];
  __shared__ __attribute__((aligned(16))) u16 Vs0[256 * 32];
  __shared__ __attribute__((aligned(16))) u16 Vs1[256 * 32];
  __shared__ __attribute__((aligned(16))) u16 Ps[4][16 * 40];

  int t = threadIdx.x;
  FlashCtx cx;
  cx.t = t; cx.lane = t & 63; cx.w = t >> 6;
  cx.lr = cx.lane & 15; cx.lq = cx.lane >> 4;

  // XCD-affine decode: group g=(bh,c) pinned to XCD g&7
  int idx = blockIdx.x;                 // 0..511
  int xcd = idx & 7, slot = idx >> 3;   // slot 0..63
  int pairI = slot & 15, ghi = slot >> 4;
  int g = ghi * 8 + xcd;                // 0..31
  int bh = g >> 1, c = g & 1;
  int b = bh >> 3, h = bh & 7;

  cx.Qbase = QKb + (size_t)b * 2048 * 4096 + h * 256 + c * 128;
  cx.Kbase = cx.Qbase + 2048;
  cx.Vbase = Vt + (size_t)(h * 256) * 4096 + b * 2048;
  u16* Op = o12b + (size_t)c * (4096ull * 2048) + (size_t)b * 2048 * 2048 + h * 256;
  u16* PsW = Ps[cx.w];

  // prologue: stage tile 0 of phase 0 into buf0
  stage_kv(cx, 0, Ks0, Vs0);

#pragma unroll 1
  for (int phase = 0; phase < 2; phase++) {
    int qi = phase ? (31 - pairI) : pairI;
    int q0 = qi * 64;
    int nst = 2 * qi + 2;   // always even

    bf16x8 qa[4];
#pragma unroll
    for (int ks = 0; ks < 4; ks++)
      qa[ks] = *(const bf16x8*)&cx.Qbase[(size_t)(q0 + cx.w * 16 + cx.lr) * 4096 +
                                         ks * 32 + cx.lq * 8];

    f32x4 acc[16] = {};
    float m_[4] = {-INFINITY, -INFINITY, -INFINITY, -INFINITY};
    float l_[4] = {};

#pragma unroll 1
    for (int jj = 0; jj < nst; jj += 2) {
      // next-tile index for each half-step; end of phase 0 prefetches phase 1's tile 0
      int n0c = (jj + 1 < nst) ? (jj + 1) * 32 : -1;
      int n1c;
      if (jj + 2 < nst) n1c = (jj + 2) * 32;
      else n1c = (phase == 0) ? 0 : -1;
      flash_step(cx, qa, jj * 32, n0c, q0, Ks0, Vs0, Ks1, Vs1, PsW, acc, m_, l_);
      flash_step(cx, qa, (jj + 1) * 32, n1c, q0, Ks1, Vs1, Ks0, Vs0, PsW, acc, m_, l_);
    }

    // epilogue: o12b[c][b*2048+row][h*256+e]
#pragma unroll
    for (int r = 0; r < 4; r++) {
      float inv = 1.0f / l_[r];
      int row = q0 + cx.w * 16 + cx.lq * 4 + r;
#pragma unroll
      for (int ei = 0; ei < 16; ei++)
        Op[(size_t)row * 2048 + ei * 16 + cx.lr] = f2bf(acc[ei][r] * inv);
    }
  }
}

// --------------------------- combine + RMSNorm -----------------------------
__global__ void combine_kernel(const u16* __restrict__ o12b, const float* __restrict__ lamp,
                               const float* __restrict__ g, u16* __restrict__ ob) {
  __shared__ float red[4];
  int t = threadIdx.x;
  int grp = blockIdx.x;  // (b*2048+tt)*8 + h
  size_t idx = (size_t)grp * 256 + t;
  const size_t comp = 4096ull * 2048;
  float lam = lamp[0];
  float v = bf2f(o12b[idx]) - lam * bf2f(o12b[idx + comp]);
  float ss = v * v;
  ss += __shfl_xor(ss, 1);
  ss += __shfl_xor(ss, 2);
  ss += __shfl_xor(ss, 4);
  ss += __shfl_xor(ss, 8);
  ss += __shfl_xor(ss, 16);
  ss += __shfl_xor(ss, 32);
  if ((t & 63) == 0) red[t >> 6] = ss;
  __syncthreads();
  float tot = red[0] + red[1] + red[2] + red[3];
  float scale = rsqrtf(tot * (1.0f / 256.0f) + 1e-5f) * (1.0f - LAMBDA_INIT);
  ob[(size_t)(grp >> 3) * 2048 + (grp & 7) * 256 + t] = f2bf(v * scale * g[t]);
}

// ---------------------------------------------------------------------------

extern "C" void kernel_launch(void* const* d_in, const int* in_sizes, int n_in,
                              void* d_out, int out_size, void* d_ws, size_t ws_size,
                              hipStream_t stream) {
  const float* x   = (const float*)d_in[0];
  const float* Wq  = (const float*)d_in[1];
  const float* Wk  = (const float*)d_in[2];
  const float* Wv  = (const float*)d_in[3];
  const float* Wo  = (const float*)d_in[4];
  const float* lq1 = (const float*)d_in[5];
  const float* lk1 = (const float*)d_in[6];
  const float* lq2 = (const float*)d_in[7];
  const float* lk2 = (const float*)d_in[8];
  const float* g   = (const float*)d_in[9];

  char* ws = (char*)d_ws;
  u16* xb    = (u16*)(ws);
  u16* Wtq   = (u16*)(ws + 16777216);
  u16* Wtk   = (u16*)(ws + 25165824);
  u16* Wtv   = (u16*)(ws + 33554432);
  u16* Wto   = (u16*)(ws + 41943040);
  u16* QKb   = (u16*)(ws + 50331648);
  u16* Vt    = (u16*)(ws + 83886080);
  u16* o12b  = (u16*)(ws + 100663296);
  u16* ob    = (u16*)(ws + 134217728);
  float* lamp = (float*)(ws + 150994944);

  cast_x_kernel<<<8192, 256, 0, stream>>>(x, xb, 2097152);
  dim3 tb(32, 8), tg(64, 64);
  transpose_w_kernel<<<tg, tb, 0, stream>>>(Wq, Wtq);
  transpose_w_kernel<<<tg, tb, 0, stream>>>(Wk, Wtk);
  transpose_w_kernel<<<tg, tb, 0, stream>>>(Wv, Wtv);
  transpose_w_kernel<<<tg, tb, 0, stream>>>(Wo, Wto);
  lam_kernel<<<1, 64, 0, stream>>>(lq1, lk1, lq2, lk2, lamp);

  // [Q|K] = x @ [Wq|Wk] : M=4096, N=4096 (Wtq,Wtk contiguous)
  gemm_bt_kernel<1><<<dim3(32, 32), 256, 0, stream>>>(xb, Wtq, QKb, 4096, 4096, 2048);
  // V^T directly: C[e][bt] = sum_k Wv[k][e] x[bt][k]  (M=2048, N=4096)
  gemm_bt_kernel<1><<<dim3(32, 16), 256, 0, stream>>>(Wtv, xb, Vt, 2048, 4096, 2048);

  flash_diff_kernel<<<512, 256, 0, stream>>>(QKb, Vt, o12b);
  combine_kernel<<<32768, 256, 0, stream>>>(o12b, lamp, g, ob);
  gemm_bt_kernel<0><<<dim3(16, 32), 256, 0, stream>>>(ob, Wto, (float*)d_out, 4096, 2048, 2048);
}

// Round 4
// 445.251 us; speedup vs baseline: 2.1814x; 1.1075x over previous
//
#include <hip/hip_runtime.h>
#include <stdint.h>
#include <math.h>

// ---------------------------------------------------------------------------
// MultiheadSdpaDiff3 round 4.
// ws layout (bytes):
//   xb   @ 0          : 16777216   (x as bf16 [4096][2048])
//   Wtq  @ 16777216   : 8388608    (Wq^T bf16 [N][K])
//   Wtk  @ 25165824   : 8388608    (contiguous after Wtq -> merged QK gemm)
//   Wtv  @ 33554432   : 8388608
//   Wto  @ 41943040   : 8388608
//   QKb  @ 50331648   : 33554432   (bf16 [4096][4096]: cols 0-2047 Q, 2048-4095 K)
//   Vt   @ 83886080   : 16777216   (bf16 [2048 e][4096 bt] = V^T, from gemm)
//   o12b @ 100663296  : 33554432   (bf16 [c][bt][h*256+e])
//   ob   @ 134217728  : 16777216   (combined+rmsnormed bf16 [4096][2048])
//   lam  @ 150994944  : 256
// ---------------------------------------------------------------------------

typedef unsigned short u16;
typedef short bf16x8 __attribute__((ext_vector_type(8)));
typedef float f32x4 __attribute__((ext_vector_type(4)));

typedef uint32_t __attribute__((address_space(1))) as1_u32;
typedef uint32_t __attribute__((address_space(3))) as3_u32;

#define LAMBDA_INIT 0.78360576653162453f

__device__ __forceinline__ u16 f2bf(float f) {
  uint32_t u = __float_as_uint(f);
  u += 0x7FFFu + ((u >> 16) & 1u);   // RNE
  return (u16)(u >> 16);
}
__device__ __forceinline__ float bf2f(u16 v) {
  return __uint_as_float(((uint32_t)v) << 16);
}

__device__ __forceinline__ void async16(u16* lds, const u16* g) {
  __builtin_amdgcn_global_load_lds((const as1_u32*)(uintptr_t)g,
                                   (as3_u32*)(uint32_t)(uintptr_t)lds, 16, 0, 0);
}

__device__ __forceinline__ f32x4 mfma16(bf16x8 a, bf16x8 b, f32x4 c) {
  return __builtin_amdgcn_mfma_f32_16x16x32_bf16(a, b, c, 0, 0, 0);
}

// --------------------------- prep kernels ----------------------------------

__global__ void cast_x_kernel(const float* __restrict__ x, u16* __restrict__ xb, int n4) {
  int i = blockIdx.x * 256 + threadIdx.x;
  if (i < n4) {
    float4 v = ((const float4*)x)[i];
    ushort4 o;
    o.x = f2bf(v.x); o.y = f2bf(v.y); o.z = f2bf(v.z); o.w = f2bf(v.w);
    ((ushort4*)xb)[i] = o;
  }
}

// Wt[n][k] = bf16(W[k][n]); W is [2048][2048] fp32.
__global__ void transpose_w_kernel(const float* __restrict__ W, u16* __restrict__ Wt) {
  __shared__ float tile[32][33];
  int tx = threadIdx.x, ty = threadIdx.y;
  int c0 = blockIdx.x * 32, r0 = blockIdx.y * 32;
#pragma unroll
  for (int i = 0; i < 32; i += 8)
    tile[ty + i][tx] = W[(size_t)(r0 + ty + i) * 2048 + c0 + tx];
  __syncthreads();
#pragma unroll
  for (int i = 0; i < 32; i += 8)
    Wt[(size_t)(c0 + ty + i) * 2048 + r0 + tx] = f2bf(tile[tx][ty + i]);
}

__global__ void lam_kernel(const float* __restrict__ lq1, const float* __restrict__ lk1,
                           const float* __restrict__ lq2, const float* __restrict__ lk2,
                           float* __restrict__ out) {
  int L = threadIdx.x;  // 64 threads
  float d1 = lq1[L] * lk1[L] + lq1[L + 64] * lk1[L + 64];
  float d2 = lq2[L] * lk2[L] + lq2[L + 64] * lk2[L + 64];
#pragma unroll
  for (int m = 1; m < 64; m <<= 1) {
    d1 += __shfl_xor(d1, m);
    d2 += __shfl_xor(d2, m);
  }
  if (L == 0) out[0] = __expf(d1) - __expf(d2) + LAMBDA_INIT;
}

// --------------------------- GEMM (m97 structure) --------------------------
template <int OUT_BF16>
__global__ __launch_bounds__(256, 2) void gemm_bt_kernel(const u16* __restrict__ A,
                                                         const u16* __restrict__ Bt,
                                                         void* __restrict__ Cout,
                                                         int M, int N, int K) {
  __shared__ __attribute__((aligned(16))) u16 As[128 * 32];
  __shared__ __attribute__((aligned(16))) u16 Bs[128 * 32];
  int t = threadIdx.x;
  int lane = t & 63, w = t >> 6;
  int lr = lane & 15, lq = lane >> 4;
  int m0 = blockIdx.y * 128, n0 = blockIdx.x * 128;
  int wm = (w >> 1) * 64, wn = (w & 1) * 64;
  const u16* Ab = A + (size_t)m0 * K;
  const u16* Bb = Bt + (size_t)n0 * K;
  f32x4 acc[4][4] = {};
  int r0 = t >> 2;
  int kc0 = (t & 3) * 8;

  for (int k0 = 0; k0 < K; k0 += 32) {
    __syncthreads();
    async16(&As[t * 8], Ab + (size_t)r0 * K + k0 + kc0);
    async16(&Bs[t * 8], Bb + (size_t)r0 * K + k0 + kc0);
    async16(&As[(256 + t) * 8], Ab + (size_t)(64 + r0) * K + k0 + kc0);
    async16(&Bs[(256 + t) * 8], Bb + (size_t)(64 + r0) * K + k0 + kc0);
    __syncthreads();
    bf16x8 a[4], b[4];
#pragma unroll
    for (int mi = 0; mi < 4; mi++)
      a[mi] = *(const bf16x8*)&As[(wm + mi * 16 + lr) * 32 + lq * 8];
#pragma unroll
    for (int ni = 0; ni < 4; ni++)
      b[ni] = *(const bf16x8*)&Bs[(wn + ni * 16 + lr) * 32 + lq * 8];
#pragma unroll
    for (int mi = 0; mi < 4; mi++)
#pragma unroll
      for (int ni = 0; ni < 4; ni++)
        acc[mi][ni] = mfma16(a[mi], b[ni], acc[mi][ni]);
  }
#pragma unroll
  for (int mi = 0; mi < 4; mi++) {
#pragma unroll
    for (int ni = 0; ni < 4; ni++) {
#pragma unroll
      for (int r = 0; r < 4; r++) {
        int row = m0 + wm + mi * 16 + lq * 4 + r;
        int col = n0 + wn + ni * 16 + lr;
        if (OUT_BF16)
          ((u16*)Cout)[(size_t)row * N + col] = f2bf(acc[mi][ni][r]);
        else
          ((float*)Cout)[(size_t)row * N + col] = acc[mi][ni][r];
      }
    }
  }
}

// --------------------------- flash attention -------------------------------
// Grid: 512 blocks 1D, XCD-affine decode. Block = 256 thr = 4 waves; wave w
// owns Q-rows [w*16,w*16+16), all 256 V-cols. Uniform pair schedule
// (qi, 31-qi). Double-buffered 32-col K/V DMA staging.
// K LDS: [32 rows][16 granules], granule low-3 XOR row&7.
// V LDS: [256 e][4 granules], granule XOR (e>>1)&3  (kills 8-way conflicts).
// Softmax: wave-uniform running max (exp2 domain); l via ones-column MFMA;
// P stored truncated-bf16 (bias cancels in PV / P*1 normalization).

struct FlashCtx {
  const u16* Qbase;
  const u16* Kbase;
  const u16* Vbase;
  int t, w, lr, lq;
};

__device__ __forceinline__ void stage_kv(const FlashCtx& cx, int jc,
                                         u16* KsN, u16* VsN) {
#pragma unroll
  for (int i = 0; i < 2; i++) {
    int q = cx.t + i * 256;
    int row = q >> 4, gp = q & 15;
    int gg = (gp & 8) | ((gp & 7) ^ (row & 7));
    async16(&KsN[q * 8], cx.Kbase + (size_t)(jc + row) * 4096 + gg * 8);
  }
#pragma unroll
  for (int i = 0; i < 4; i++) {
    int q = cx.t + i * 256;
    int e = q >> 2, gp = q & 3;
    int gg = gp ^ ((e >> 1) & 3);
    async16(&VsN[q * 8], cx.Vbase + (size_t)e * 4096 + jc + gg * 8);
  }
}

__device__ __forceinline__ void flash_step(const FlashCtx& cx, const bf16x8* qa,
                                           int jc, int njc, int q0,
                                           const u16* KsC, const u16* VsC,
                                           u16* KsN, u16* VsN, u16* PsW,
                                           f32x4* acc, f32x4* lacc, float* m_) {
  __syncthreads();              // joins prev compute; drains DMA for KsC/VsC
  if (njc >= 0) stage_kv(cx, njc, KsN, VsN);   // overlaps with compute below

  if (jc > q0 + cx.w * 16 + 15) return;        // wave-uniform skip
  const float k2 = 0.12753257550036097f;       // log2(e)/sqrt(128)
  int lr = cx.lr, lq = cx.lq;

  // S = Q K^T : 16 rows x 32 cols per wave
  f32x4 sacc[2] = {};
#pragma unroll
  for (int ks = 0; ks < 4; ks++) {
#pragma unroll
    for (int ni = 0; ni < 2; ni++) {
      int row = ni * 16 + lr;
      int g = ks * 4 + lq;
      int gp = (g & 8) | ((g & 7) ^ (row & 7));
      bf16x8 kb = *(const bf16x8*)&KsC[row * 128 + gp * 8];
      sacc[ni] = mfma16(qa[ks], kb, sacc[ni]);
    }
  }

  // scores in exp2 domain + causal mask (diag tiles only)
  float s2[2][4];
  bool diag = (jc >= q0);
#pragma unroll
  for (int ni = 0; ni < 2; ni++)
#pragma unroll
    for (int r = 0; r < 4; r++) {
      float v = sacc[ni][r] * k2;
      if (diag) {
        int colg = jc + ni * 16 + lr;
        int rowg = q0 + cx.w * 16 + lq * 4 + r;
        if (colg > rowg) v = -INFINITY;
      }
      s2[ni][r] = v;
    }

  // wave-level running max
  float mv = fmaxf(fmaxf(fmaxf(s2[0][0], s2[0][1]), fmaxf(s2[0][2], s2[0][3])),
                   fmaxf(fmaxf(s2[1][0], s2[1][1]), fmaxf(s2[1][2], s2[1][3])));
  mv = fmaxf(mv, __shfl_xor(mv, 1));
  mv = fmaxf(mv, __shfl_xor(mv, 2));
  mv = fmaxf(mv, __shfl_xor(mv, 4));
  mv = fmaxf(mv, __shfl_xor(mv, 8));
  mv = fmaxf(mv, __shfl_xor(mv, 16));
  mv = fmaxf(mv, __shfl_xor(mv, 32));
  float mo = *m_;
  float mn = fmaxf(mo, mv);
  *m_ = mn;
  float a = __builtin_amdgcn_exp2f(mo - mn);   // -inf -> 0

  // P (truncated bf16; consistent with l via ones-MFMA)
#pragma unroll
  for (int ni = 0; ni < 2; ni++)
#pragma unroll
    for (int r = 0; r < 4; r++) {
      float p = __builtin_amdgcn_exp2f(s2[ni][r] - mn);
      PsW[(lq * 4 + r) * 40 + ni * 16 + lr] = (u16)(__float_as_uint(p) >> 16);
    }

  if (a != 1.0f) {   // wave-uniform at runtime
#pragma unroll
    for (int ei = 0; ei < 16; ei++)
#pragma unroll
      for (int r = 0; r < 4; r++) acc[ei][r] *= a;
#pragma unroll
    for (int r = 0; r < 4; r++) (*lacc)[r] *= a;
  }

  // O += P @ V ; l += P @ 1  (P wave-private in LDS; same-wave write->read)
  const bf16x8 onesb = {0x3F80, 0x3F80, 0x3F80, 0x3F80, 0x3F80, 0x3F80, 0x3F80, 0x3F80};
  bf16x8 pa = *(const bf16x8*)&PsW[lr * 40 + lq * 8];
#pragma unroll
  for (int ei = 0; ei < 16; ei++) {
    int row = ei * 16 + lr;
    int gp = lq ^ ((row >> 1) & 3);
    bf16x8 vb = *(const bf16x8*)&VsC[row * 32 + gp * 8];
    acc[ei] = mfma16(pa, vb, acc[ei]);
  }
  *lacc = mfma16(pa, onesb, *lacc);
}

__global__ __launch_bounds__(256, 2) void flash_diff_kernel(const u16* __restrict__ QKb,
                                                            const u16* __restrict__ Vt,
                                                            u16* __restrict__ o12b) {
  __shared__ __attribute__((aligned(16))) u16 Ks0[32 * 128];
  __shared__ __attribute__((aligned(16))) u16 Ks1[32 * 128];
  __shared__ __attribute__((aligned(16))) u16 Vs0[256 * 32];
  __shared__ __attribute__((aligned(16))) u16 Vs1[256 * 32];
  __shared__ __attribute__((aligned(16))) u16 Ps[4][16 * 40];

  int t = threadIdx.x;
  FlashCtx cx;
  cx.t = t; cx.w = t >> 6;
  cx.lr = t & 15; cx.lq = (t >> 4) & 3;

  // XCD-affine decode: group g=(bh,c) pinned to XCD g&7
  int idx = blockIdx.x;                 // 0..511
  int xcd = idx & 7, slot = idx >> 3;   // slot 0..63
  int pairI = slot & 15, ghi = slot >> 4;
  int g = ghi * 8 + xcd;                // 0..31
  int bh = g >> 1, c = g & 1;
  int b = bh >> 3, h = bh & 7;

  cx.Qbase = QKb + (size_t)b * 2048 * 4096 + h * 256 + c * 128;
  cx.Kbase = cx.Qbase + 2048;
  cx.Vbase = Vt + (size_t)(h * 256) * 4096 + b * 2048;
  u16* Op = o12b + (size_t)c * (4096ull * 2048) + (size_t)b * 2048 * 2048 + h * 256;
  u16* PsW = Ps[cx.w];

  // prologue: stage tile 0 of phase 0 into buf0
  stage_kv(cx, 0, Ks0, Vs0);

#pragma unroll 1
  for (int phase = 0; phase < 2; phase++) {
    int qi = phase ? (31 - pairI) : pairI;
    int q0 = qi * 64;
    int nst = 2 * qi + 2;   // always even

    bf16x8 qa[4];
#pragma unroll
    for (int ks = 0; ks < 4; ks++)
      qa[ks] = *(const bf16x8*)&cx.Qbase[(size_t)(q0 + cx.w * 16 + cx.lr) * 4096 +
                                         ks * 32 + cx.lq * 8];

    f32x4 acc[16] = {};
    f32x4 lacc = {};
    float m_ = -INFINITY;

#pragma unroll 1
    for (int jj = 0; jj < nst; jj += 2) {
      int n0c = (jj + 1 < nst) ? (jj + 1) * 32 : -1;
      int n1c;
      if (jj + 2 < nst) n1c = (jj + 2) * 32;
      else n1c = (phase == 0) ? 0 : -1;
      flash_step(cx, qa, jj * 32, n0c, q0, Ks0, Vs0, Ks1, Vs1, PsW, acc, &lacc, &m_);
      flash_step(cx, qa, (jj + 1) * 32, n1c, q0, Ks1, Vs1, Ks0, Vs0, PsW, acc, &lacc, &m_);
    }

    // epilogue: o12b[c][b*2048+row][h*256+e]
#pragma unroll
    for (int r = 0; r < 4; r++) {
      float inv = 1.0f / lacc[r];
      int row = q0 + cx.w * 16 + cx.lq * 4 + r;
#pragma unroll
      for (int ei = 0; ei < 16; ei++)
        Op[(size_t)row * 2048 + ei * 16 + cx.lr] = f2bf(acc[ei][r] * inv);
    }
  }
}

// --------------------------- combine + RMSNorm -----------------------------
__global__ void combine_kernel(const u16* __restrict__ o12b, const float* __restrict__ lamp,
                               const float* __restrict__ g, u16* __restrict__ ob) {
  __shared__ float red[4];
  int t = threadIdx.x;
  int grp = blockIdx.x;  // (b*2048+tt)*8 + h
  size_t idx = (size_t)grp * 256 + t;
  const size_t comp = 4096ull * 2048;
  float lam = lamp[0];
  float v = bf2f(o12b[idx]) - lam * bf2f(o12b[idx + comp]);
  float ss = v * v;
  ss += __shfl_xor(ss, 1);
  ss += __shfl_xor(ss, 2);
  ss += __shfl_xor(ss, 4);
  ss += __shfl_xor(ss, 8);
  ss += __shfl_xor(ss, 16);
  ss += __shfl_xor(ss, 32);
  if ((t & 63) == 0) red[t >> 6] = ss;
  __syncthreads();
  float tot = red[0] + red[1] + red[2] + red[3];
  float scale = rsqrtf(tot * (1.0f / 256.0f) + 1e-5f) * (1.0f - LAMBDA_INIT);
  ob[(size_t)(grp >> 3) * 2048 + (grp & 7) * 256 + t] = f2bf(v * scale * g[t]);
}

// ---------------------------------------------------------------------------

extern "C" void kernel_launch(void* const* d_in, const int* in_sizes, int n_in,
                              void* d_out, int out_size, void* d_ws, size_t ws_size,
                              hipStream_t stream) {
  const float* x   = (const float*)d_in[0];
  const float* Wq  = (const float*)d_in[1];
  const float* Wk  = (const float*)d_in[2];
  const float* Wv  = (const float*)d_in[3];
  const float* Wo  = (const float*)d_in[4];
  const float* lq1 = (const float*)d_in[5];
  const float* lk1 = (const float*)d_in[6];
  const float* lq2 = (const float*)d_in[7];
  const float* lk2 = (const float*)d_in[8];
  const float* g   = (const float*)d_in[9];

  char* ws = (char*)d_ws;
  u16* xb    = (u16*)(ws);
  u16* Wtq   = (u16*)(ws + 16777216);
  u16* Wtk   = (u16*)(ws + 25165824);
  u16* Wtv   = (u16*)(ws + 33554432);
  u16* Wto   = (u16*)(ws + 41943040);
  u16* QKb   = (u16*)(ws + 50331648);
  u16* Vt    = (u16*)(ws + 83886080);
  u16* o12b  = (u16*)(ws + 100663296);
  u16* ob    = (u16*)(ws + 134217728);
  float* lamp = (float*)(ws + 150994944);

  cast_x_kernel<<<8192, 256, 0, stream>>>(x, xb, 2097152);
  dim3 tb(32, 8), tg(64, 64);
  transpose_w_kernel<<<tg, tb, 0, stream>>>(Wq, Wtq);
  transpose_w_kernel<<<tg, tb, 0, stream>>>(Wk, Wtk);
  transpose_w_kernel<<<tg, tb, 0, stream>>>(Wv, Wtv);
  transpose_w_kernel<<<tg, tb, 0, stream>>>(Wo, Wto);
  lam_kernel<<<1, 64, 0, stream>>>(lq1, lk1, lq2, lk2, lamp);

  // [Q|K] = x @ [Wq|Wk] : M=4096, N=4096 (Wtq,Wtk contiguous)
  gemm_bt_kernel<1><<<dim3(32, 32), 256, 0, stream>>>(xb, Wtq, QKb, 4096, 4096, 2048);
  // V^T directly: C[e][bt] = sum_k Wv[k][e] x[bt][k]  (M=2048, N=4096)
  gemm_bt_kernel<1><<<dim3(32, 16), 256, 0, stream>>>(Wtv, xb, Vt, 2048, 4096, 2048);

  flash_diff_kernel<<<512, 256, 0, stream>>>(QKb, Vt, o12b);
  combine_kernel<<<32768, 256, 0, stream>>>(o12b, lamp, g, ob);
  gemm_bt_kernel<0><<<dim3(16, 32), 256, 0, stream>>>(ob, Wto, (float*)d_out, 4096, 2048, 2048);
}